// Round 4
// baseline (447.728 us; speedup 1.0000x reference)
//
#include <hip/hip_runtime.h>

// Fused ReconstructionHead: h = x[:, :-1] @ W1^T + b1; LayerNorm*gamma+beta;
// relu; out[b,t] = dot(h, Wout[t]) + bout[t].  M = 131072 rows, K = N = 512.
//
// R4 vs R3 (184 us, 1 block/CU, MfmaUtil 15%):
//  - wave tile 64x128 (acc[4][8]): 32 MFMA per 12 ds_read_b128 per wave-chunk
//    (was 16:10) -> LDS-read bytes per FLOP down 40%
//  - MT=64, 256 threads (4 waves), dbuf A+B = 78.3 KB LDS -> 2 blocks/CU:
//    intra-block DMA/compute overlap AND inter-block barrier cover (m97/m114)
//  - __launch_bounds__(256,2): 256-VGPR cap (est ~185, no spill)
//  - XOR k-swizzle removed (proven no-op on bank distribution)

#define DIN     512
#define BK      32
#define MT      64            // rows per block
#define THREADS 256           // 4 waves; wave w owns cols [w*128, w*128+128)
#define NCHUNK  (DIN / BK)    // 16
#define ASTR    40            // A row stride in shorts (32 + 8 pad; 80 B = 5*16)
#define BROW    32            // B row stride in shorts (64 B, DMA-contiguous)

typedef __attribute__((ext_vector_type(8))) short bf16x8;
typedef __attribute__((ext_vector_type(4))) float f32x4;

__device__ __forceinline__ short f2bf(float f) {
    unsigned u = __float_as_uint(f);
    u = u + 0x7fffu + ((u >> 16) & 1u);   // RNE
    return (short)(u >> 16);
}

__device__ __forceinline__ void gload_lds16(const void* g, void* l) {
    __builtin_amdgcn_global_load_lds(
        (const __attribute__((address_space(1))) unsigned int*)g,
        (__attribute__((address_space(3))) unsigned int*)l,
        16, 0, 0);
}

__global__ void cvt_w1_kernel(const float* __restrict__ w, short* __restrict__ o) {
    int i = blockIdx.x * blockDim.x + threadIdx.x;   // 65536 threads, 4 elems each
    float4 v = ((const float4*)w)[i];
    short4 s;
    s.x = f2bf(v.x); s.y = f2bf(v.y); s.z = f2bf(v.z); s.w = f2bf(v.w);
    ((short4*)o)[i] = s;
}

// fallback staging (no bf16 W1 workspace): 256 threads stage 512 rows x BK
__device__ __forceinline__ void stage_b_f32(short* bsb, const float* W1f,
                                            int c, int tid) {
#pragma unroll
    for (int h = 0; h < 2; ++h) {
        int row = tid * 2 + h;
        const float* src = W1f + (size_t)row * DIN + c * BK;
#pragma unroll
        for (int g = 0; g < 2; ++g) {
            float4 v0 = *(const float4*)(src + g * 8);
            float4 v1 = *(const float4*)(src + g * 8 + 4);
            bf16x8 s;
            s[0] = f2bf(v0.x); s[1] = f2bf(v0.y); s[2] = f2bf(v0.z); s[3] = f2bf(v0.w);
            s[4] = f2bf(v1.x); s[5] = f2bf(v1.y); s[6] = f2bf(v1.z); s[7] = f2bf(v1.w);
            *(bf16x8*)(bsb + row * BROW + g * 8) = s;
        }
    }
}

template<bool WS>
__global__ __launch_bounds__(THREADS, 2)
void fused_head_kernel(const float* __restrict__ x,
                       const float* __restrict__ W1f,
                       const short* __restrict__ W1h,
                       const float* __restrict__ b1,
                       const float* __restrict__ gamma,
                       const float* __restrict__ beta,
                       const float* __restrict__ Wout,
                       const float* __restrict__ bout,
                       float* __restrict__ out) {
    __shared__ __align__(16) short As[2][MT * ASTR];    // 10240 B
    __shared__ __align__(16) short Bs[2][DIN * BROW];   // 65536 B
    __shared__ float redS[MT][4];                       // 1024 B
    __shared__ float redQ[MT][4];                       // 1024 B
    __shared__ float meanA[MT];
    __shared__ float rstdA[MT];                         // total 78336 B -> 2/CU

    const int tid  = threadIdx.x;
    const int w    = tid >> 6;        // wave 0..3 = col group
    const int lane = tid & 63;
    const int q    = lane >> 4;       // quad 0..3
    const int l15  = lane & 15;

    const int m0 = blockIdx.x * MT;
    const int bb = m0 >> 9;           // batch index
    const int t0 = m0 & 511;          // first t (multiple of 64)
    const float* xbase = x + (size_t)(bb * 513 + t0) * DIN;

    // A staging: 256 threads cover 64 rows x 32 k fp32 (8 floats each)
    const int ar = tid >> 2;          // row 0..63
    const int ak = (tid & 3) * 8;     // k offset (floats)

    // B DMA: wave w stages rows [w*128, w*128+128) as 8 x 1KB instrs (16 rows
    // each). lane i: row += i>>2, k-shorts (i&3)*8; LDS = base + i*16B.
    const short* bG = W1h + (size_t)(w * 128 + (lane >> 2)) * DIN + (lane & 3) * 8;

    f32x4 acc[4][8];
#pragma unroll
    for (int i = 0; i < 4; ++i)
#pragma unroll
        for (int j = 0; j < 8; ++j)
            acc[i][j] = (f32x4){0.f, 0.f, 0.f, 0.f};

    // ---- prologue: stage chunk 0 into buffer 0, prefetch A chunk 1 ----
    float4 a0 = *(const float4*)(xbase + ar * DIN + ak);
    float4 a1 = *(const float4*)(xbase + ar * DIN + ak + 4);
    if (WS) {
#pragma unroll
        for (int j = 0; j < 8; ++j)
            gload_lds16(bG + (size_t)(j * 16) * DIN,
                        &Bs[0][(w * 128 + j * 16) * BROW]);
    } else {
        stage_b_f32(&Bs[0][0], W1f, 0, tid);
    }
    {
        bf16x8 s;
        s[0] = f2bf(a0.x); s[1] = f2bf(a0.y); s[2] = f2bf(a0.z); s[3] = f2bf(a0.w);
        s[4] = f2bf(a1.x); s[5] = f2bf(a1.y); s[6] = f2bf(a1.z); s[7] = f2bf(a1.w);
        *(bf16x8*)(&As[0][ar * ASTR + ak]) = s;
    }
    a0 = *(const float4*)(xbase + ar * DIN + BK + ak);
    a1 = *(const float4*)(xbase + ar * DIN + BK + ak + 4);

    for (int c = 0; c < NCHUNK; ++c) {
        const int cur = c & 1, nxt = cur ^ 1;
        __syncthreads();   // chunk c staged; buf nxt's readers done
        if (c + 1 < NCHUNK) {
            if (WS) {
                const short* g = bG + (size_t)(c + 1) * BK;
#pragma unroll
                for (int j = 0; j < 8; ++j)
                    gload_lds16(g + (size_t)(j * 16) * DIN,
                                &Bs[nxt][(w * 128 + j * 16) * BROW]);
            } else {
                stage_b_f32(&Bs[nxt][0], W1f, c + 1, tid);
            }
            bf16x8 s;
            s[0] = f2bf(a0.x); s[1] = f2bf(a0.y); s[2] = f2bf(a0.z); s[3] = f2bf(a0.w);
            s[4] = f2bf(a1.x); s[5] = f2bf(a1.y); s[6] = f2bf(a1.z); s[7] = f2bf(a1.w);
            *(bf16x8*)(&As[nxt][ar * ASTR + ak]) = s;
            if (c + 2 < NCHUNK) {
                a0 = *(const float4*)(xbase + ar * DIN + (c + 2) * BK + ak);
                a1 = *(const float4*)(xbase + ar * DIN + (c + 2) * BK + ak + 4);
            }
        }
        // ---- compute chunk c from buffer cur (overlaps in-flight DMA) ----
        bf16x8 af[4];
        const short* Ap = &As[cur][l15 * ASTR + q * 8];
#pragma unroll
        for (int ti = 0; ti < 4; ++ti)
            af[ti] = *(const bf16x8*)(Ap + ti * 16 * ASTR);
        const short* Bp = &Bs[cur][(w * 128 + l15) * BROW + q * 8];
#pragma unroll
        for (int tj = 0; tj < 8; ++tj) {
            bf16x8 bf = *(const bf16x8*)(Bp + tj * 16 * BROW);
#pragma unroll
            for (int ti = 0; ti < 4; ++ti)
                acc[ti][tj] = __builtin_amdgcn_mfma_f32_16x16x32_bf16(
                    af[ti], bf, acc[ti][tj], 0, 0, 0);
        }
    }

    // ================= epilogue =================
    float b1v[8], gv[8], bv[8];
    const int cb = w * 128 + l15;
#pragma unroll
    for (int tj = 0; tj < 8; ++tj) {
        int col = cb + tj * 16;
        b1v[tj] = b1[col];
        gv[tj]  = gamma[col];
        bv[tj]  = beta[col];
    }

    // pass 1: row sums / sumsq.  C layout: col = l15, row = ti*16 + q*4 + r
#pragma unroll
    for (int ti = 0; ti < 4; ++ti)
#pragma unroll
        for (int r = 0; r < 4; ++r) {
            int row = ti * 16 + q * 4 + r;
            float s = 0.f, s2 = 0.f;
#pragma unroll
            for (int tj = 0; tj < 8; ++tj) {
                float v = acc[ti][tj][r] + b1v[tj];
                s += v; s2 += v * v;
            }
#pragma unroll
            for (int m = 1; m < 16; m <<= 1) {
                s  += __shfl_xor(s,  m, 64);
                s2 += __shfl_xor(s2, m, 64);
            }
            if (l15 == 0) { redS[row][w] = s; redQ[row][w] = s2; }
        }
    __syncthreads();
    if (tid < MT) {
        float s  = redS[tid][0] + redS[tid][1] + redS[tid][2] + redS[tid][3];
        float s2 = redQ[tid][0] + redQ[tid][1] + redQ[tid][2] + redQ[tid][3];
        float mean = s * (1.f / DIN);
        float var  = s2 * (1.f / DIN) - mean * mean;
        meanA[tid] = mean;
        rstdA[tid] = rsqrtf(fmaxf(var, 0.f) + 1e-5f);
    }
    __syncthreads();

    // pass 2: normalize + relu + dot with Wout[t]
#pragma unroll
    for (int ti = 0; ti < 4; ++ti)
#pragma unroll
        for (int r = 0; r < 4; ++r) {
            int row = ti * 16 + q * 4 + r;
            float mean = meanA[row], rs = rstdA[row];
            const float* wrow = Wout + (size_t)(t0 + row) * DIN + cb;
            float s = 0.f;
#pragma unroll
            for (int tj = 0; tj < 8; ++tj) {
                float v = acc[ti][tj][r] + b1v[tj];
                v = (v - mean) * rs * gv[tj] + bv[tj];
                v = fmaxf(v, 0.f);
                s += v * wrow[tj * 16];
            }
#pragma unroll
            for (int m = 1; m < 16; m <<= 1)
                s += __shfl_xor(s, m, 64);
            if (l15 == 0) redS[row][w] = s;
        }
    __syncthreads();
    if (tid < MT)
        out[m0 + tid] = redS[tid][0] + redS[tid][1] + redS[tid][2] + redS[tid][3]
                        + bout[t0 + tid];
}

extern "C" void kernel_launch(void* const* d_in, const int* in_sizes, int n_in,
                              void* d_out, int out_size, void* d_ws, size_t ws_size,
                              hipStream_t stream) {
    const float* x     = (const float*)d_in[0];
    const float* W1    = (const float*)d_in[1];
    const float* b1    = (const float*)d_in[2];
    const float* gamma = (const float*)d_in[3];
    const float* beta  = (const float*)d_in[4];
    const float* Wout  = (const float*)d_in[5];
    const float* bout  = (const float*)d_in[6];
    float* out = (float*)d_out;

    const int M = 256 * 512;
    dim3 grid(M / MT), block(THREADS);

    if (ws_size >= (size_t)(DIN * DIN) * sizeof(short)) {
        short* W1h = (short*)d_ws;
        cvt_w1_kernel<<<DIN * DIN / (256 * 4), 256, 0, stream>>>(W1, W1h);
        fused_head_kernel<true><<<grid, block, 0, stream>>>(
            x, W1, W1h, b1, gamma, beta, Wout, bout, out);
    } else {
        fused_head_kernel<false><<<grid, block, 0, stream>>>(
            x, W1, nullptr, b1, gamma, beta, Wout, bout, out);
    }
}